// Round 1
// baseline (852.350 us; speedup 1.0000x reference)
//
#include <hip/hip_runtime.h>
#include <stdint.h>

// ---------------------------------------------------------------------------
// Fused transformer block: LN1 -> qkv -> causal flash attn -> out-proj(+res)
//                          -> LN2 -> gelu-FFN(+res) -> halt head
// bf16 MFMA (16x16x32) for all matmuls; fp32 residual stream.
// ---------------------------------------------------------------------------

typedef unsigned short u16;
typedef __attribute__((ext_vector_type(8))) short short8v;   // 8 bf16 = 4 VGPR
typedef __attribute__((ext_vector_type(4))) float f32x4;     // MFMA C/D frag
typedef __attribute__((ext_vector_type(4))) u16 u16x4;

#define B_ 4
#define N_ 2048
#define D_ 1024
#define H_ 16
#define DH_ 64
#define ROWS_ (B_ * N_)   // 8192

__device__ __forceinline__ u16 f2bf(float f) {
  union { float f; unsigned u; } v; v.f = f;
  unsigned r = v.u + 0x7fffu + ((v.u >> 16) & 1u);   // RNE
  return (u16)(r >> 16);
}

// MFMA via inline asm (avoids builtin-signature ambiguity). C operand comes
// from a previous MFMA or a far-away init -> no extra wait states needed.
__device__ __forceinline__ f32x4 mfma_b(short8v a, short8v b, f32x4 c) {
  asm volatile("v_mfma_f32_16x16x32_bf16 %0, %1, %2, %0" : "+v"(c) : "v"(a), "v"(b));
  return c;
}
// Variant for C freshly written by VALU (zero init / alpha rescale): cover the
// VALU-write -> MFMA-read hazard manually (inline asm bypasses the recognizer).
__device__ __forceinline__ f32x4 mfma_b_vc(short8v a, short8v b, f32x4 c) {
  asm volatile("s_nop 1\n\tv_mfma_f32_16x16x32_bf16 %0, %1, %2, %0" : "+v"(c) : "v"(a), "v"(b));
  return c;
}
// Pass-through fence before VALU reads of MFMA results.
__device__ __forceinline__ f32x4 accfence(f32x4 v) {
  asm volatile("s_nop 7" : "+v"(v));
  return v;
}

// async global->LDS, 16B per lane. LDS side must be wave-uniform base + lane*16.
__device__ __forceinline__ void async16(const void* g, void* l) {
  __builtin_amdgcn_global_load_lds((__attribute__((address_space(1))) unsigned int*)g,
                                   (__attribute__((address_space(3))) unsigned int*)l,
                                   16, 0, 0);
}

// ---------------------------------------------------------------------------
// LayerNorm over D=1024, fp32 in -> bf16 out. One block (256 thr) per row.
// ---------------------------------------------------------------------------
__global__ __launch_bounds__(256) void ln_kernel(const float* __restrict__ x,
    const float* __restrict__ gam, const float* __restrict__ bet,
    u16* __restrict__ out) {
  const int row = blockIdx.x;
  const int t = threadIdx.x;
  const float4 v = ((const float4*)(x + (size_t)row * D_))[t];
  float s  = v.x + v.y + v.z + v.w;
  float ss = v.x*v.x + v.y*v.y + v.z*v.z + v.w*v.w;
#pragma unroll
  for (int o = 32; o >= 1; o >>= 1) { s += __shfl_xor(s, o); ss += __shfl_xor(ss, o); }
  __shared__ float red[8];
  const int w = t >> 6;
  if ((t & 63) == 0) { red[w] = s; red[4 + w] = ss; }
  __syncthreads();
  s  = red[0] + red[1] + red[2] + red[3];
  ss = red[4] + red[5] + red[6] + red[7];
  const float mean = s * (1.0f / D_);
  const float var  = ss * (1.0f / D_) - mean * mean;
  const float rstd = rsqrtf(var + 1e-5f);
  const float4 g4 = ((const float4*)gam)[t];
  const float4 b4 = ((const float4*)bet)[t];
  u16x4 o4;
  o4.x = f2bf((v.x - mean) * rstd * g4.x + b4.x);
  o4.y = f2bf((v.y - mean) * rstd * g4.y + b4.y);
  o4.z = f2bf((v.z - mean) * rstd * g4.z + b4.z);
  o4.w = f2bf((v.w - mean) * rstd * g4.w + b4.w);
  *(u16x4*)(out + (size_t)row * D_ + t * 4) = o4;
}

// ---------------------------------------------------------------------------
// Weight transpose + cast: W[K][N] fp32 -> WT[N][K] bf16 (GEMM wants B^T).
// ---------------------------------------------------------------------------
__global__ __launch_bounds__(256) void transpose_cast(const float* __restrict__ W,
    u16* __restrict__ WT, int K, int N) {
  __shared__ float tile[32][33];
  const int n0 = blockIdx.x * 32, k0 = blockIdx.y * 32;
  const int tx = threadIdx.x, ty = threadIdx.y;
#pragma unroll
  for (int i = 0; i < 4; ++i)
    tile[ty + i * 8][tx] = W[(size_t)(k0 + ty + i * 8) * N + n0 + tx];
  __syncthreads();
#pragma unroll
  for (int i = 0; i < 4; ++i)
    WT[(size_t)(n0 + ty + i * 8) * K + k0 + tx] = f2bf(tile[tx][ty + i * 8]);
}

// V transpose: qkv bf16 v-part -> vt[b][h][d][n] so PV B-frags read contiguous.
__global__ __launch_bounds__(256) void transpose_v(const u16* __restrict__ qkv,
    u16* __restrict__ vt) {
  __shared__ u16 tile[32][33];
  const int bh = blockIdx.z;
  const int bb = bh >> 4, hh = bh & 15;
  const int n0 = blockIdx.x * 32, d0 = blockIdx.y * 32;
  const int tx = threadIdx.x, ty = threadIdx.y;
#pragma unroll
  for (int i = 0; i < 4; ++i)
    tile[ty + i * 8][tx] =
        qkv[(size_t)(bb * N_ + n0 + ty + i * 8) * 3072 + 2048 + hh * DH_ + d0 + tx];
  __syncthreads();
#pragma unroll
  for (int i = 0; i < 4; ++i)
    vt[((size_t)bh * DH_ + d0 + ty + i * 8) * N_ + n0 + tx] = tile[tx][ty + i * 8];
}

// ---------------------------------------------------------------------------
// bf16 MFMA GEMM, m97-style: C[M,N] = A[M,K] @ BT[N,K]^T, 128x128 block tile,
// BK=32, 4 waves in 2x2, each wave 4x4 16x16 frags. Epilogue modes:
//   0: store bf16            2: gelu(C+bias) -> bf16
//   1/3: C + bias + res -> fp32
// ---------------------------------------------------------------------------
__global__ __launch_bounds__(256) void gemm_bt(
    const u16* __restrict__ A, const u16* __restrict__ BT,
    int N, int K, int mode,
    const float* __restrict__ bias, const float* __restrict__ res,
    float* __restrict__ outf, u16* __restrict__ outb) {
  __shared__ alignas(16) u16 As[128 * 32];
  __shared__ alignas(16) u16 Bs[128 * 32];
  const int t = threadIdx.x;
  const int lane = t & 63, w = t >> 6;
  const int wm = w >> 1, wn = w & 1;
  const int cc = lane & 15, quad = lane >> 4;
  const int m0 = blockIdx.y * 128, n0 = blockIdx.x * 128;

  const f32x4 fz = {0.f, 0.f, 0.f, 0.f};
  f32x4 acc[4][4];
#pragma unroll
  for (int i = 0; i < 4; ++i)
#pragma unroll
    for (int j = 0; j < 4; ++j) acc[i][j] = fz;

  const int off0 = t * 16;
  for (int k0 = 0; k0 < K; k0 += 32) {
#pragma unroll
    for (int r = 0; r < 2; ++r) {
      const int off = r * 4096 + off0;          // byte offset in 8KB tile
      const int row = off >> 6;                 // 64B per row (32 bf16)
      const int col = (off & 63) >> 1;
      async16(A  + (size_t)(m0 + row) * K + k0 + col, (char*)As + off);
      async16(BT + (size_t)(n0 + row) * K + k0 + col, (char*)Bs + off);
    }
    __syncthreads();   // drains vmcnt -> tiles resident
    short8v a[4], b[4];
#pragma unroll
    for (int i = 0; i < 4; ++i)
      a[i] = *(const short8v*)(As + (wm * 64 + i * 16 + cc) * 32 + quad * 8);
#pragma unroll
    for (int j = 0; j < 4; ++j)
      b[j] = *(const short8v*)(Bs + (wn * 64 + j * 16 + cc) * 32 + quad * 8);
#pragma unroll
    for (int i = 0; i < 4; ++i)
#pragma unroll
      for (int j = 0; j < 4; ++j) acc[i][j] = mfma_b(a[i], b[j], acc[i][j]);
    __syncthreads();
  }

#pragma unroll
  for (int i = 0; i < 4; ++i) {
    const int row = m0 + wm * 64 + i * 16 + quad * 4;
#pragma unroll
    for (int j = 0; j < 4; ++j) {
      const int col = n0 + wn * 64 + j * 16 + cc;
      f32x4 v = accfence(acc[i][j]);
#pragma unroll
      for (int r = 0; r < 4; ++r) {
        const size_t idx = (size_t)(row + r) * N + col;
        float val = v[r];
        if (mode == 0) {
          outb[idx] = f2bf(val);
        } else if (mode == 2) {
          val += bias[col];
          val = 0.5f * val * (1.0f + erff(val * 0.70710678118654752f));
          outb[idx] = f2bf(val);
        } else {  // 1 or 3: fp32 residual epilogue
          outf[idx] = val + bias[col] + res[idx];
        }
      }
    }
  }
}

// ---------------------------------------------------------------------------
// Causal flash attention. Block = 4 waves, Q-tile 64 (16 rows/wave), K-tile 64.
// Online softmax state per lane (4 rows, replicated over 16 lanes of a quad).
// P goes C-layout -> LDS -> A-layout (m120-verified round trip).
// ---------------------------------------------------------------------------
__global__ __launch_bounds__(256) void attn_kernel(const u16* __restrict__ qkv,
    const u16* __restrict__ vt, u16* __restrict__ outp) {
  const int qb = blockIdx.x, hh = blockIdx.y, bb = blockIdx.z;
  const int t = threadIdx.x, lane = t & 63, w = t >> 6;
  const int cc = lane & 15, quad = lane >> 4;
  const int q0 = qb * 64;
  __shared__ alignas(16) u16 Qs[64 * 64];
  __shared__ alignas(16) u16 Ks[64 * 64];
  __shared__ alignas(16) u16 Vs[64 * 64];     // [d][key]
  __shared__ alignas(16) u16 Ps[4][16 * 72];  // pitch 72 breaks write conflicts

  const int off0 = t * 16;
#pragma unroll
  for (int r = 0; r < 2; ++r) {
    const int off = r * 4096 + off0;
    const int rw = off >> 7, cb = (off & 127) >> 1;   // 128B per 64-elem row
    async16(qkv + (size_t)(bb * N_ + q0 + rw) * 3072 + hh * DH_ + cb, (char*)Qs + off);
  }
  __syncthreads();
  short8v qa[2];
#pragma unroll
  for (int kh = 0; kh < 2; ++kh)
    qa[kh] = *(const short8v*)(Qs + (w * 16 + cc) * 64 + kh * 32 + quad * 8);

  const f32x4 fz = {0.f, 0.f, 0.f, 0.f};
  f32x4 of[4];
#pragma unroll
  for (int n = 0; n < 4; ++n) of[n] = fz;
  float m_run[4], l_run[4];
#pragma unroll
  for (int r = 0; r < 4; ++r) { m_run[r] = -3.0e38f; l_run[r] = 0.f; }

  for (int kt = 0; kt <= qb; ++kt) {
    const int k0 = kt * 64;
    __syncthreads();   // all waves done with previous Ks/Vs
#pragma unroll
    for (int r = 0; r < 2; ++r) {
      const int off = r * 4096 + off0;
      const int rw = off >> 7, cb = (off & 127) >> 1;
      async16(qkv + (size_t)(bb * N_ + k0 + rw) * 3072 + 1024 + hh * DH_ + cb,
              (char*)Ks + off);
      async16(vt + ((size_t)(bb * H_ + hh) * DH_ + rw) * N_ + k0 + cb,
              (char*)Vs + off);
    }
    __syncthreads();

    // S = Q K^T  (two MFMAs over dh=64 per 16-key chunk)
    f32x4 s[4];
#pragma unroll
    for (int j = 0; j < 4; ++j) {
      const short8v kb0 = *(const short8v*)(Ks + (j * 16 + cc) * 64 + quad * 8);
      const short8v kb1 = *(const short8v*)(Ks + (j * 16 + cc) * 64 + 32 + quad * 8);
      f32x4 z = fz;
      z = mfma_b_vc(qa[0], kb0, z);
      z = mfma_b(qa[1], kb1, z);
      s[j] = accfence(z);
    }
    // scale + causal mask + online softmax (rows = quad*4+r, cols = lane&15)
    const int qrow = q0 + w * 16 + quad * 4;
    float mt[4];
#pragma unroll
    for (int r = 0; r < 4; ++r) {
      float mx = -3.0e38f;
#pragma unroll
      for (int j = 0; j < 4; ++j) {
        float sv = s[j][r] * 0.125f;                  // DH^-0.5
        if (k0 + j * 16 + cc > qrow + r) sv = -3.0e38f;
        s[j][r] = sv;
        mx = fmaxf(mx, sv);
      }
      mt[r] = mx;
    }
#pragma unroll
    for (int o = 1; o < 16; o <<= 1) {
#pragma unroll
      for (int r = 0; r < 4; ++r) mt[r] = fmaxf(mt[r], __shfl_xor(mt[r], o));
    }
    float alpha[4], rs[4];
#pragma unroll
    for (int r = 0; r < 4; ++r) {
      const float mnew = fmaxf(m_run[r], mt[r]);
      alpha[r] = __expf(m_run[r] - mnew);
      m_run[r] = mnew;
      float a = 0.f;
#pragma unroll
      for (int j = 0; j < 4; ++j) {
        const float p = __expf(s[j][r] - mnew);
        s[j][r] = p;
        a += p;
      }
      rs[r] = a;
    }
#pragma unroll
    for (int o = 1; o < 16; o <<= 1) {
#pragma unroll
      for (int r = 0; r < 4; ++r) rs[r] += __shfl_xor(rs[r], o);
    }
#pragma unroll
    for (int r = 0; r < 4; ++r) l_run[r] = l_run[r] * alpha[r] + rs[r];
    // P: C-layout -> LDS (bf16)
#pragma unroll
    for (int r = 0; r < 4; ++r)
#pragma unroll
      for (int j = 0; j < 4; ++j)
        Ps[w][(quad * 4 + r) * 72 + j * 16 + cc] = f2bf(s[j][r]);
    __syncthreads();
    // O = alpha*O + P V
    short8v pa[2];
#pragma unroll
    for (int kh = 0; kh < 2; ++kh)
      pa[kh] = *(const short8v*)(&Ps[w][cc * 72 + kh * 32 + quad * 8]);
#pragma unroll
    for (int n = 0; n < 4; ++n) {
      f32x4 o = of[n];
#pragma unroll
      for (int r = 0; r < 4; ++r) o[r] *= alpha[r];
      const short8v vb0 = *(const short8v*)(Vs + (n * 16 + cc) * 64 + quad * 8);
      const short8v vb1 = *(const short8v*)(Vs + (n * 16 + cc) * 64 + 32 + quad * 8);
      o = mfma_b_vc(pa[0], vb0, o);
      o = mfma_b(pa[1], vb1, o);
      of[n] = o;
    }
  }
#pragma unroll
  for (int n = 0; n < 4; ++n) {
    f32x4 o = accfence(of[n]);
#pragma unroll
    for (int r = 0; r < 4; ++r) {
      const size_t row = (size_t)(bb * N_ + q0 + w * 16 + quad * 4 + r);
      outp[row * 1024 + hh * DH_ + n * 16 + cc] = f2bf(o[r] / l_run[r]);
    }
  }
}

// ---------------------------------------------------------------------------
// Halt head: hout[b] = mean_n(x[b]) @ w_halt + b_halt
// ---------------------------------------------------------------------------
__global__ void halt_init(float* __restrict__ hout, const float* __restrict__ bh) {
  if (threadIdx.x < B_) hout[threadIdx.x] = bh[0];
}

__global__ __launch_bounds__(256) void halt_partial(const float* __restrict__ xf,
    const float* __restrict__ wh, float* __restrict__ hout) {
  const int bb = blockIdx.y, sl = blockIdx.x;
  const size_t base = ((size_t)bb * N_ + sl * 64) * D_;
  float p = 0.f;
  for (int e = threadIdx.x; e < 64 * D_; e += 256)
    p += xf[base + e] * wh[e & (D_ - 1)];
#pragma unroll
  for (int o = 32; o >= 1; o >>= 1) p += __shfl_xor(p, o);
  __shared__ float red[4];
  const int w = threadIdx.x >> 6;
  if ((threadIdx.x & 63) == 0) red[w] = p;
  __syncthreads();
  if (threadIdx.x == 0)
    atomicAdd(&hout[bb], (red[0] + red[1] + red[2] + red[3]) * (1.0f / N_));
}

// ---------------------------------------------------------------------------
extern "C" void kernel_launch(void* const* d_in, const int* in_sizes, int n_in,
                              void* d_out, int out_size, void* d_ws, size_t ws_size,
                              hipStream_t stream) {
  (void)in_sizes; (void)n_in; (void)out_size; (void)ws_size;
  const float* x      = (const float*)d_in[0];
  const float* ln1_g  = (const float*)d_in[1];
  const float* ln1_b  = (const float*)d_in[2];
  const float* w_qkv  = (const float*)d_in[3];
  const float* w_out  = (const float*)d_in[4];
  const float* b_out  = (const float*)d_in[5];
  const float* ln2_g  = (const float*)d_in[6];
  const float* ln2_b  = (const float*)d_in[7];
  const float* w_ff1  = (const float*)d_in[8];
  const float* b_ff1  = (const float*)d_in[9];
  const float* w_ff2  = (const float*)d_in[10];
  const float* b_ff2  = (const float*)d_in[11];
  const float* w_halt = (const float*)d_in[12];
  const float* b_halt = (const float*)d_in[13];

  float* out_x    = (float*)d_out;                       // [8192,1024] fp32
  float* out_halt = out_x + (size_t)ROWS_ * D_;          // [4]

  // Workspace layout (bytes). Persistent transposed bf16 weights, then a
  // liveness-overlapped scratch region. Total ~104 MB.
  char* ws = (char*)d_ws;
  u16* wqkvT = (u16*)(ws + 0);           //  6291456  [3072,1024]
  u16* woutT = (u16*)(ws + 6291456);     //  2097152  [1024,1024]
  u16* wff1T = (u16*)(ws + 8388608);     //  8388608  [4096,1024]
  u16* wff2T = (u16*)(ws + 16777216);    //  8388608  [1024,4096]
  char* RB   = ws + 25165824;
  u16* qkvb  = (u16*)(RB);               // 50331648  [8192,3072] (dead after attn)
  u16* h1    = (u16*)(RB + 50331648);    // 16777216  (dead after qkv gemm)
  u16* attno = h1;                       // aliases h1 (dead after out-proj)
  u16* vtb   = (u16*)(RB + 67108864);    // 16777216  (dead after attn)
  u16* h2    = (u16*)(RB);               // aliases qkvb
  u16* ff1b  = (u16*)(RB + 16777216);    // 67108864  aliases vtb/attno tail

  const dim3 tb(32, 8);
  // 1) weights -> bf16 transposed
  transpose_cast<<<dim3(96, 32),  tb, 0, stream>>>(w_qkv, wqkvT, 1024, 3072);
  transpose_cast<<<dim3(32, 32),  tb, 0, stream>>>(w_out, woutT, 1024, 1024);
  transpose_cast<<<dim3(128, 32), tb, 0, stream>>>(w_ff1, wff1T, 1024, 4096);
  transpose_cast<<<dim3(32, 128), tb, 0, stream>>>(w_ff2, wff2T, 4096, 1024);
  // 2) LN1
  ln_kernel<<<ROWS_, 256, 0, stream>>>(x, ln1_g, ln1_b, h1);
  // 3) qkv = h1 @ w_qkv  -> bf16
  gemm_bt<<<dim3(24, 64), 256, 0, stream>>>(h1, wqkvT, 3072, 1024, 0,
                                            nullptr, nullptr, nullptr, qkvb);
  // 4) V -> [b,h,d,n]
  transpose_v<<<dim3(64, 2, 64), tb, 0, stream>>>(qkvb, vtb);
  // 5) causal flash attention
  attn_kernel<<<dim3(32, 16, 4), 256, 0, stream>>>(qkvb, vtb, attno);
  // 6) x1 = attn @ w_out + b_out + x   (fp32, into d_out)
  gemm_bt<<<dim3(8, 64), 256, 0, stream>>>(attno, woutT, 1024, 1024, 1,
                                           b_out, x, out_x, nullptr);
  // 7) LN2
  ln_kernel<<<ROWS_, 256, 0, stream>>>(out_x, ln2_g, ln2_b, h2);
  // 8) ff1 = gelu(h2 @ w_ff1 + b_ff1) -> bf16
  gemm_bt<<<dim3(32, 64), 256, 0, stream>>>(h2, wff1T, 4096, 1024, 2,
                                            b_ff1, nullptr, nullptr, ff1b);
  // 9) x = ff1 @ w_ff2 + b_ff2 + x1   (in-place on d_out; per-element RMW)
  gemm_bt<<<dim3(8, 64), 256, 0, stream>>>(ff1b, wff2T, 1024, 4096, 3,
                                           b_ff2, out_x, out_x, nullptr);
  // 10) halt
  halt_init<<<1, 64, 0, stream>>>(out_halt, b_halt);
  halt_partial<<<dim3(32, 4), 256, 0, stream>>>(out_x, w_halt, out_halt);
}